// Round 9
// baseline (178.980 us; speedup 1.0000x reference)
//
#include <hip/hip_runtime.h>
#include <hip/hip_bf16.h>

// Shapes: B=8, N=1024, D=768, H=12, HD=64, 3D=2304, tokens M=8192.
// Workspace layout (bytes), total 55,050,240 (~52.5 MiB):
//   xb   @ 0         : [8192][768]  bf16 (x * gate; reused as attn-out later)
//   wtq  @ 12582912  : [2304][768]  bf16 (W_qkv^T)
//   wtm  @ 16121856  : [768][768]   bf16 (W_msa^T)
//   qb   @ 17301504  : [B,H,N,64]   bf16 (q * SCALE * log2e)
//   kb   @ 29884416  : [B,H,N,64]   bf16 (k)
//   vt   @ 42467328  : [B,H,64,N]   bf16 (v, transposed)

typedef __attribute__((ext_vector_type(8))) short bf8;   // 8 x bf16 (4 VGPRs)
typedef __attribute__((ext_vector_type(4))) float f4;

#define QSCALE 0.1803368801111204f  // (1/8) * log2(e): exp2-domain logits
#define MFMA16 __builtin_amdgcn_mfma_f32_16x16x32_bf16

static __device__ __forceinline__ short bf16_of(float f) {
    union { float f; unsigned u; } a; a.f = f;
    unsigned r = a.u + 0x7FFFu + ((a.u >> 16) & 1u);  // RNE
    return (short)(r >> 16);
}

static __device__ __forceinline__ unsigned bfpk(float lo, float hi) {
    float2 t; t.x = lo; t.y = hi;
    __hip_bfloat162 b = __float22bfloat162_rn(t);
    union { __hip_bfloat162 b; unsigned u; } c; c.b = b;
    return c.u;
}

// async global->LDS, 16 bytes/lane. LDS dest must be wave-uniform base + lane*16.
static __device__ __forceinline__ void async16(const short* g, short* l) {
    __builtin_amdgcn_global_load_lds(
        (const __attribute__((address_space(1))) void*)g,
        (__attribute__((address_space(3))) void*)l, 16, 0, 0);
}

// ---- merged prep kernel: cvt (blocks 0..3071) + Wqkv transpose (3072..3503)
//      + Wmsa transpose (3504..3647). Independent work; saves 2 launch gaps.
static __device__ __forceinline__ void transpose64(
        const float* __restrict__ w, short* __restrict__ wt,
        int K, int E, int k0, int e0, int tid, short (*t)[65]) {
#pragma unroll
    for (int p = 0; p < 16; ++p) {
        int idx = p * 256 + tid;
        int r = idx >> 6, c = idx & 63;
        t[r][c] = bf16_of(w[(k0 + r) * E + e0 + c]);
    }
    __syncthreads();
#pragma unroll
    for (int p = 0; p < 16; ++p) {
        int idx = p * 256 + tid;
        int r = idx >> 6, c = idx & 63;     // r = e offset, c = k offset
        wt[(e0 + r) * K + k0 + c] = t[c][r];
    }
}

__global__ __launch_bounds__(256) void k_prep(
        const float* __restrict__ x, const float* __restrict__ gate,
        short* __restrict__ xb,
        const float* __restrict__ Wqkv, short* __restrict__ wtq,
        const float* __restrict__ Wmsa, short* __restrict__ wtm) {
    __shared__ short t[64][65];
    const int bid = blockIdx.x, tid = threadIdx.x;
    if (bid < 3072) {
        int i = bid * 256 + tid;              // 786432 = 8192*768/8 exactly
        const float g = gate[i / 96];         // row = i*8/768
        const f4* sp = (const f4*)x;
        f4 a = sp[2 * i], b = sp[2 * i + 1];
        union { bf8 v; short h[8]; } o;
        o.h[0] = bf16_of(a[0] * g); o.h[1] = bf16_of(a[1] * g);
        o.h[2] = bf16_of(a[2] * g); o.h[3] = bf16_of(a[3] * g);
        o.h[4] = bf16_of(b[0] * g); o.h[5] = bf16_of(b[1] * g);
        o.h[6] = bf16_of(b[2] * g); o.h[7] = bf16_of(b[3] * g);
        ((bf8*)xb)[i] = o.v;
    } else if (bid < 3504) {
        int tt = bid - 3072;                  // 432 = 36 x 12
        transpose64(Wqkv, wtq, 768, 2304, (tt / 36) * 64, (tt % 36) * 64, tid, t);
    } else {
        int tt = bid - 3504;                  // 144 = 12 x 12
        transpose64(Wmsa, wtm, 768, 768, (tt / 12) * 64, (tt % 12) * 64, tid, t);
    }
}

// ---- QKV projection: [8192,768] @ [768,2304], tile 128x144, BK=64.
// (R8 structure, verified): 256-thread block at 2 blocks/CU = 8 waves/CU =
// 2 waves/SIMD -> full 256-reg budget per wave; the co-resident partner block
// cross-hides the per-tile drain stall (m97 mechanism).
// 4 waves as 4M x 1N -> per-wave 32x144 = acc[2][9] = 72 AGPR; no spill.
// Grid 64m x 16n = 1024 blocks = exactly 4 per CU: zero tail, zero imbalance.
// LDS double buffer 2 x 17408 shorts = 68 KiB -> 2 blocks/CU.
// Proven slot^(row&7) XOR swizzle (2 lanes/bank on ds_read_b128).
__global__ __launch_bounds__(256, 2) void k_gemm_qkv(
        const short* __restrict__ xb, const short* __restrict__ wtq,
        short* __restrict__ qb, short* __restrict__ kb, short* __restrict__ vt) {
    __shared__ short lds[34816];   // 2 x 17408 shorts = 68 KiB
    const int tid = threadIdx.x, lane = tid & 63;
    const int l16 = lane & 15, quad = lane >> 4, rx = l16 & 7;
    const int wm = tid >> 6;       // 4 M-waves; every wave covers all 144 cols

    // XCD swizzle: 1024 blocks = 8 XCDs x 128; each XCD: 8 mI x all 16 nI
    // (B 3.5 MB ~ one XCD L2; A 8x128 rows = 1.6 MB).
    const int wg = blockIdx.x;
    const int swz = (wg & 7) * 128 + (wg >> 3);
    const int mI = swz >> 4, nI = swz & 15;
    const int m0 = mI * 128, n0 = nI * 144;

    const short* gA = xb + m0 * 768;
    const short* gB = wtq + n0 * 768;

    auto stageA = [&](int buf, int k0) {        // 128x64 = 1024 chunks, 4/thr
        short* base = lds + buf * 17408;
#pragma unroll
        for (int j = 0; j < 4; ++j) {
            int p = j * 256 + tid, row = p >> 3;
            int gc = (p & 7) ^ (row & 7);
            async16(gA + row * 768 + k0 + gc * 8, base + p * 8);
        }
    };
    auto stageB = [&](int buf, int k0) {        // 144x64 = 1152 chunks
        short* base = lds + buf * 17408 + 8192;
#pragma unroll
        for (int j = 0; j < 4; ++j) {
            int p = j * 256 + tid, row = p >> 3;
            int gc = (p & 7) ^ (row & 7);
            async16(gB + row * 768 + k0 + gc * 8, base + p * 8);
        }
        if (tid < 128) {            // waves 0,1 take the extra 128 chunks
            int p = 1024 + tid, row = p >> 3;
            int gc = (p & 7) ^ (row & 7);
            async16(gB + row * 768 + k0 + gc * 8, base + p * 8);
        }
    };

    auto rdA = [&](const short* base, int mf, int ks) {
        return *(const bf8*)(base + (wm * 32 + mf * 16 + l16) * 64 +
                             (((ks * 4 + quad) ^ rx) << 3));
    };
    auto rdB = [&](const short* base, int nf, int ks) {
        return *(const bf8*)(base + 8192 + (nf * 16 + l16) * 64 +
                             (((ks * 4 + quad) ^ rx) << 3));
    };

    f4 z = {0.f, 0.f, 0.f, 0.f};
    f4 acc[2][9];
#pragma unroll
    for (int mf = 0; mf < 2; ++mf)
#pragma unroll
        for (int nf = 0; nf < 9; ++nf) acc[mf][nf] = z;

    stageA(0, 0); stageB(0, 0);
    asm volatile("s_waitcnt vmcnt(0)" ::: "memory");
    __builtin_amdgcn_s_barrier();

#pragma unroll 2
    for (int t = 0; t < 12; ++t) {
        const short* cur = lds + (t & 1) * 17408;
        // ---- phase 1: nf 0-4 ----
        bf8 af[2][2];
        af[0][0] = rdA(cur, 0, 0); af[0][1] = rdA(cur, 0, 1);
        af[1][0] = rdA(cur, 1, 0); af[1][1] = rdA(cur, 1, 1);
        bf8 bfr[5][2];
#pragma unroll
        for (int nf = 0; nf < 5; ++nf) { bfr[nf][0] = rdB(cur, nf, 0); bfr[nf][1] = rdB(cur, nf, 1); }
        if (t < 11) stageA((t + 1) & 1, (t + 1) * 64);
        __builtin_amdgcn_s_setprio(1);
#pragma unroll
        for (int mf = 0; mf < 2; ++mf)
#pragma unroll
            for (int nf = 0; nf < 5; ++nf) {
                acc[mf][nf] = MFMA16(af[mf][0], bfr[nf][0], acc[mf][nf], 0, 0, 0);
                acc[mf][nf] = MFMA16(af[mf][1], bfr[nf][1], acc[mf][nf], 0, 0, 0);
            }
        __builtin_amdgcn_s_setprio(0);
        // ---- phase 2: nf 5-8 ----
        bf8 bfh[4][2];
#pragma unroll
        for (int nf = 0; nf < 4; ++nf) { bfh[nf][0] = rdB(cur, nf + 5, 0); bfh[nf][1] = rdB(cur, nf + 5, 1); }
        if (t < 11) stageB((t + 1) & 1, (t + 1) * 64);
        __builtin_amdgcn_s_setprio(1);
#pragma unroll
        for (int mf = 0; mf < 2; ++mf)
#pragma unroll
            for (int nf = 0; nf < 4; ++nf) {
                acc[mf][nf + 5] = MFMA16(af[mf][0], bfh[nf][0], acc[mf][nf + 5], 0, 0, 0);
                acc[mf][nf + 5] = MFMA16(af[mf][1], bfh[nf][1], acc[mf][nf + 5], 0, 0, 0);
            }
        __builtin_amdgcn_s_setprio(0);
        // drain own stage(t+1) -> next buffer resident after barrier; the
        // co-resident second block on this CU hides the drain stall.
        asm volatile("s_waitcnt vmcnt(0)" ::: "memory");
        __builtin_amdgcn_s_barrier();
    }

    // ---------------- epilogue ----------------
    const int bI = m0 >> 10, nn0 = m0 & 1023;
    // q/k frags: direct stores (frags never straddle q/k/v; 768 % 16 == 0)
#pragma unroll
    for (int nf = 0; nf < 9; ++nf) {
        const int ct = n0 + nf * 16;
        if (ct < 1536) {
            const int which = (ct >= 768) ? 1 : 0;
            const int h = (ct - which * 768) >> 6;
            const int hd = (ct & 63) + l16;
            short* dst = (which ? kb : qb) + (bI * 12 + h) * 65536 + hd;
#pragma unroll
            for (int mf = 0; mf < 2; ++mf)
#pragma unroll
                for (int r = 0; r < 4; ++r) {
                    const int nn = nn0 + wm * 32 + mf * 16 + quad * 4 + r;
                    const float val = acc[mf][nf][r];
                    dst[nn * 64] = bf16_of(which ? val : val * QSCALE);
                }
        }
    }
    // v frags: transpose through LDS in 48-col passes (48 x 136 shorts).
    const int vlo = (n0 >= 1536) ? n0 : 1536;
    const int vcnt = n0 + 144 - vlo;
    const int npass = (vcnt > 0) ? vcnt / 48 : 0;
    for (int p = 0; p < npass; ++p) {
        __syncthreads();
        const int c0 = vlo + p * 48;
#pragma unroll
        for (int nf = 0; nf < 9; ++nf) {
            const int ct = n0 + nf * 16;
            if (ct >= c0 && ct < c0 + 48) {
                const int lcol = ct - c0 + l16;        // 0..47
#pragma unroll
                for (int mf = 0; mf < 2; ++mf)
#pragma unroll
                    for (int r = 0; r < 4; ++r) {
                        const int row = wm * 32 + mf * 16 + quad * 4 + r;
                        lds[lcol * 136 + row] = bf16_of(acc[mf][nf][r]);
                    }
            }
        }
        __syncthreads();
        const int vg0 = c0 - 1536;
#pragma unroll
        for (int u = 0; u < 3; ++u) {
            const int idx = u * 256 + tid;     // 48 cols x 16 chunks = 768
            const int lc = idx >> 4, ck = idx & 15;
            const int vg = vg0 + lc;
            const int h = vg >> 6, hd = vg & 63;
            bf8 vv = *(const bf8*)(lds + lc * 136 + ck * 8);
            *(bf8*)(vt + ((bI * 12 + h) * 64 + hd) * 1024 + nn0 + ck * 8) = vv;
        }
    }
}

// ---- final projection: [8192,768] @ [768,768] + bias -> fp32 out.
// R8-qkv structure ported (round-8 theory): tile 128x96, BK=64, 256 thr as
// 4M x 1N waves -> per-wave 32x96 = acc[2][6] = 48 AGPR. Grid 64m x 8n = 512
// blocks = exactly 2 blocks/CU (vs old 384-block half-capacity imbalance);
// LDS dbuf 2 x 14336 shorts = 56 KiB; partner block hides the drain stall.
// B = 1.2 MB: fully L2-resident per XCD.
__global__ __launch_bounds__(256, 2) void k_gemm_final(
        const short* __restrict__ attn, const short* __restrict__ wtm,
        const float* __restrict__ bias, float* __restrict__ out) {
    __shared__ short lds[28672];   // 2 x 14336 shorts = 56 KiB
    const int tid = threadIdx.x, lane = tid & 63;
    const int l16 = lane & 15, quad = lane >> 4, rx = l16 & 7;
    const int wm = tid >> 6;       // 4 M-waves; every wave covers all 96 cols

    // XCD swizzle: 512 blocks = 8 XCDs x 64; each XCD: 8 mI x all 8 nI.
    const int wg = blockIdx.x;
    const int swz = (wg & 7) * 64 + (wg >> 3);
    const int mI = swz >> 3, nI = swz & 7;
    const int m0 = mI * 128, n0 = nI * 96;

    const short* gA = attn + m0 * 768;
    const short* gB = wtm + n0 * 768;

    auto stageA = [&](int buf, int k0) {        // 128x64 = 1024 chunks, 4/thr
        short* base = lds + buf * 14336;
#pragma unroll
        for (int j = 0; j < 4; ++j) {
            int p = j * 256 + tid, row = p >> 3;
            int gc = (p & 7) ^ (row & 7);
            async16(gA + row * 768 + k0 + gc * 8, base + p * 8);
        }
    };
    auto stageB = [&](int buf, int k0) {        // 96x64 = 768 chunks, 3/thr
        short* base = lds + buf * 14336 + 8192;
#pragma unroll
        for (int j = 0; j < 3; ++j) {
            int p = j * 256 + tid, row = p >> 3;
            int gc = (p & 7) ^ (row & 7);
            async16(gB + row * 768 + k0 + gc * 8, base + p * 8);
        }
    };
    auto rdA = [&](const short* base, int mf, int ks) {
        return *(const bf8*)(base + (wm * 32 + mf * 16 + l16) * 64 +
                             (((ks * 4 + quad) ^ rx) << 3));
    };
    auto rdB = [&](const short* base, int nf, int ks) {
        return *(const bf8*)(base + 8192 + (nf * 16 + l16) * 64 +
                             (((ks * 4 + quad) ^ rx) << 3));
    };

    f4 z = {0.f, 0.f, 0.f, 0.f};
    f4 acc[2][6];
#pragma unroll
    for (int mf = 0; mf < 2; ++mf)
#pragma unroll
        for (int nf = 0; nf < 6; ++nf) acc[mf][nf] = z;

    stageA(0, 0); stageB(0, 0);
    asm volatile("s_waitcnt vmcnt(0)" ::: "memory");
    __builtin_amdgcn_s_barrier();

#pragma unroll 2
    for (int t = 0; t < 12; ++t) {
        const short* cur = lds + (t & 1) * 14336;
        // ---- phase 1: nf 0-2 ----
        bf8 af[2][2];
        af[0][0] = rdA(cur, 0, 0); af[0][1] = rdA(cur, 0, 1);
        af[1][0] = rdA(cur, 1, 0); af[1][1] = rdA(cur, 1, 1);
        bf8 bfr[3][2];
#pragma unroll
        for (int nf = 0; nf < 3; ++nf) { bfr[nf][0] = rdB(cur, nf, 0); bfr[nf][1] = rdB(cur, nf, 1); }
        if (t < 11) stageA((t + 1) & 1, (t + 1) * 64);
        __builtin_amdgcn_s_setprio(1);
#pragma unroll
        for (int mf = 0; mf < 2; ++mf)
#pragma unroll
            for (int nf = 0; nf < 3; ++nf) {
                acc[mf][nf] = MFMA16(af[mf][0], bfr[nf][0], acc[mf][nf], 0, 0, 0);
                acc[mf][nf] = MFMA16(af[mf][1], bfr[nf][1], acc[mf][nf], 0, 0, 0);
            }
        __builtin_amdgcn_s_setprio(0);
        // ---- phase 2: nf 3-5 ----
        bf8 bfh[3][2];
#pragma unroll
        for (int nf = 0; nf < 3; ++nf) { bfh[nf][0] = rdB(cur, nf + 3, 0); bfh[nf][1] = rdB(cur, nf + 3, 1); }
        if (t < 11) stageB((t + 1) & 1, (t + 1) * 64);
        __builtin_amdgcn_s_setprio(1);
#pragma unroll
        for (int mf = 0; mf < 2; ++mf)
#pragma unroll
            for (int nf = 0; nf < 3; ++nf) {
                acc[mf][nf + 3] = MFMA16(af[mf][0], bfh[nf][0], acc[mf][nf + 3], 0, 0, 0);
                acc[mf][nf + 3] = MFMA16(af[mf][1], bfh[nf][1], acc[mf][nf + 3], 0, 0, 0);
            }
        __builtin_amdgcn_s_setprio(0);
        asm volatile("s_waitcnt vmcnt(0)" ::: "memory");
        __builtin_amdgcn_s_barrier();
    }

    // epilogue: fp32 + bias
#pragma unroll
    for (int nf = 0; nf < 6; ++nf) {
        const int e = n0 + nf * 16 + l16;
        const float bv = bias[e];
#pragma unroll
        for (int mf = 0; mf < 2; ++mf)
#pragma unroll
            for (int r = 0; r < 4; ++r) {
                const int row = m0 + wm * 32 + mf * 16 + quad * 4 + r;
                out[row * 768 + e] = acc[mf][nf][r] + bv;
            }
    }
}

// ---- flash attention: 4 waves x 32 q-rows (256-thread block), grid (96,8)
//      = 768 blocks -> exactly 3 co-resident blocks/CU (launch_bounds(256,3)).
// Two q-groups per wave SHARE the K and V LDS fragments: ds_read per MFMA
// halves, per-wave ILP doubles, barrier cost per unit work halves.
// Blocks are independent (no cross-block lockstep) -> setprio(1) around MFMA
// clusters pays here (T5, m191: +4-7% attn; null only on barrier-locked GEMM).
// S-MFMA set A uses K rows sigma(p)=8*(p>>2)+(p&3), set B rows sigma(p)+4.
// lane(l16,quad) regs [A0..A3,B0..B3] = P[m=l16][j=quad*8+0..7]: the PV
// B-operand directly -- no cross-lane transform needed.
// LDS swizzle f(row)=4*((row>>3)&1)+(row&3) keeps sigma-reads at 2 lanes/bank.
__global__ __launch_bounds__(256, 3) void k_attn(const short* __restrict__ qb,
                                                 const short* __restrict__ kb,
                                                 const short* __restrict__ vt,
                                                 short* __restrict__ attn) {
    __shared__ short Ks[2][4096];     // [64 keys][8 slots], f-swizzled
    __shared__ short Vs[2][4096];     // [64 dims][8 slots], f-swizzled
    const int tid = threadIdx.x, wave = tid >> 6, lane = tid & 63;
    const int l16 = lane & 15, quad = lane >> 4;
    const int bh = blockIdx.x;             // b*12 + h
    const int b = bh / 12, h = bh - b * 12;
    const int m_base = blockIdx.y * 128 + wave * 32;  // 32 q-rows per wave
    const short* qh = qb + bh * 65536;
    const short* kh = kb + bh * 65536;
    const short* vh = vt + bh * 65536;     // [64][1024]

    // K-read offsets: set A row rA = sigma(l16), set B row rA+4 (f identical)
    const int rA = ((l16 >> 2) << 3) + (l16 & 3);
    const int fK = (((rA >> 3) & 1) << 2) + (rA & 3);
    const int sK = (quad ^ fK) * 8;              // slot*8 for d-chunk=quad
    const int oAlo = rA * 64 + sK;               // d 0..31
    const int oAhi = rA * 64 + (sK ^ 32);        // d 32..63 (slot^4)
    const int oBlo = oAlo + 256, oBhi = oAhi + 256;  // row+4
    // V-read offset: row = dt*16+l16, chunk = (jj>>3)+quad
    const int fV = (((l16 >> 3) & 1) << 2) + (l16 & 3);
    const int oV = l16 * 64 + ((quad ^ fV) * 8); // jj=32 -> ^32

    // Q^T b-frags for both 16-row groups (fixed for whole loop)
    const short* qp0 = qh + (m_base + l16) * 64 + quad * 8;
    bf8 qf00 = *(const bf8*)(qp0);
    bf8 qf01 = *(const bf8*)(qp0 + 32);
    const short* qp1 = qp0 + 16 * 64;
    bf8 qf10 = *(const bf8*)(qp1);
    bf8 qf11 = *(const bf8*)(qp1 + 32);

    union { bf8 v; short h[8]; } onef;
#pragma unroll
    for (int i = 0; i < 8; ++i) onef.h[i] = (short)0x3F80;  // bf16 1.0

    f4 z = {0.f, 0.f, 0.f, 0.f};
    f4 acc0[4] = {z, z, z, z};             // out^T group 0: 4 d-tiles
    f4 acc1[4] = {z, z, z, z};             // out^T group 1
    f4 accl0 = z, accl1 = z;               // P row-sums via ones-MFMA

    auto stage = [&](int buf, int j0) {
        // 256 threads x 2: 512 chunks each for K and V
#pragma unroll
        for (int j = 0; j < 2; ++j) {
            int idx = j * 256 + tid;
            int row = idx >> 3;
            int fr = (((row >> 3) & 1) << 2) + (row & 3);
            int gc = (idx & 7) ^ fr;        // slot idx&7 holds chunk gc
            async16(kh + (j0 + row) * 64 + gc * 8, Ks[buf] + idx * 8);
            async16(vh + row * 1024 + j0 + gc * 8, Vs[buf] + idx * 8);
        }
    };

    stage(0, 0);
    int cur = 0;
    for (int it = 0; it < 16; ++it) {
        __builtin_amdgcn_s_waitcnt(0);         // own DMA for tile[cur] drained
        __syncthreads();                       // => tile[cur] resident for all
        if (it + 1 < 16) stage(cur ^ 1, (it + 1) * 64);  // overlaps compute
        const short* Kc = Ks[cur];
        const short* Vc = Vs[cur];

#pragma unroll
        for (int jj = 0; jj < 64; jj += 32) {
            const short* kjj = Kc + jj * 64;
            bf8 kAlo = *(const bf8*)(kjj + oAlo);
            bf8 kAhi = *(const bf8*)(kjj + oAhi);
            bf8 kBlo = *(const bf8*)(kjj + oBlo);
            bf8 kBhi = *(const bf8*)(kjj + oBhi);
            bf8 vf0 = *(const bf8*)(Vc + 0 * 1024 + (oV ^ (jj ? 32 : 0)));
            bf8 vf1 = *(const bf8*)(Vc + 1 * 1024 + (oV ^ (jj ? 32 : 0)));
            bf8 vf2 = *(const bf8*)(Vc + 2 * 1024 + (oV ^ (jj ? 32 : 0)));
            bf8 vf3 = *(const bf8*)(Vc + 3 * 1024 + (oV ^ (jj ? 32 : 0)));

            // ----- group 0 -----
            {
                f4 sA = z, sB = z;
                __builtin_amdgcn_s_setprio(1);
                sA = MFMA16(kAlo, qf00, sA, 0, 0, 0);
                sA = MFMA16(kAhi, qf01, sA, 0, 0, 0);
                sB = MFMA16(kBlo, qf00, sB, 0, 0, 0);
                sB = MFMA16(kBhi, qf01, sB, 0, 0, 0);
                __builtin_amdgcn_s_setprio(0);
                float a0 = __builtin_amdgcn_exp2f(sA[0]);
                float a1 = __builtin_amdgcn_exp2f(sA[1]);
                float a2 = __builtin_amdgcn_exp2f(sA[2]);
                float a3 = __builtin_amdgcn_exp2f(sA[3]);
                float b0 = __builtin_amdgcn_exp2f(sB[0]);
                float b1 = __builtin_amdgcn_exp2f(sB[1]);
                float b2 = __builtin_amdgcn_exp2f(sB[2]);
                float b3 = __builtin_amdgcn_exp2f(sB[3]);
                union { bf8 v; unsigned u[4]; } p;
                p.u[0] = bfpk(a0, a1); p.u[1] = bfpk(a2, a3);
                p.u[2] = bfpk(b0, b1); p.u[3] = bfpk(b2, b3);
                __builtin_amdgcn_s_setprio(1);
                accl0 = MFMA16(onef.v, p.v, accl0, 0, 0, 0);
                acc0[0] = MFMA16(vf0, p.v, acc0[0], 0, 0, 0);
                acc0[1] = MFMA16(vf1, p.v, acc0[1], 0, 0, 0);
                acc0[2] = MFMA16(vf2, p.v, acc0[2], 0, 0, 0);
                acc0[3] = MFMA16(vf3, p.v, acc0[3], 0, 0, 0);
                __builtin_amdgcn_s_setprio(0);
            }
            // ----- group 1 (shares kA/kB/vf frags) -----
            {
                f4 sA = z, sB = z;
                __builtin_amdgcn_s_setprio(1);
                sA = MFMA16(kAlo, qf10, sA, 0, 0, 0);
                sA = MFMA16(kAhi, qf11, sA, 0, 0, 0);
                sB = MFMA16(kBlo, qf10, sB, 0, 0, 0);
                sB = MFMA16(kBhi, qf11, sB, 0, 0, 0);
                __builtin_amdgcn_s_setprio(0);
                float a0 = __builtin_amdgcn_exp2f(sA[0]);
                float a1 = __builtin_amdgcn_exp2f(sA[1]);
                float a2 = __builtin_amdgcn_exp2f(sA[2]);
                float a3 = __builtin_amdgcn_exp2f(sA[3]);
                float b0 = __builtin_amdgcn_exp2f(sB[0]);
                float b1 = __builtin_amdgcn_exp2f(sB[1]);
                float b2 = __builtin_amdgcn_exp2f(sB[2]);
                float b3 = __builtin_amdgcn_exp2f(sB[3]);
                union { bf8 v; unsigned u[4]; } p;
                p.u[0] = bfpk(a0, a1); p.u[1] = bfpk(a2, a3);
                p.u[2] = bfpk(b0, b1); p.u[3] = bfpk(b2, b3);
                __builtin_amdgcn_s_setprio(1);
                accl1 = MFMA16(onef.v, p.v, accl1, 0, 0, 0);
                acc1[0] = MFMA16(vf0, p.v, acc1[0], 0, 0, 0);
                acc1[1] = MFMA16(vf1, p.v, acc1[1], 0, 0, 0);
                acc1[2] = MFMA16(vf2, p.v, acc1[2], 0, 0, 0);
                acc1[3] = MFMA16(vf3, p.v, acc1[3], 0, 0, 0);
                __builtin_amdgcn_s_setprio(0);
            }
        }
        cur ^= 1;
    }

    const float inv0 = 1.f / accl0[0];
    const float inv1 = 1.f / accl1[0];
    const int row0 = (b << 10) + m_base + l16;
    short* op0 = attn + row0 * 768 + h * 64 + quad * 4;
    short* op1 = op0 + 16 * 768;
#pragma unroll
    for (int dt = 0; dt < 4; ++dt)
#pragma unroll
        for (int r = 0; r < 4; ++r) {
            op0[dt * 16 + r] = bf16_of(acc0[dt][r] * inv0);
            op1[dt * 16 + r] = bf16_of(acc1[dt][r] * inv1);
        }
}

extern "C" void kernel_launch(void* const* d_in, const int* in_sizes, int n_in,
                              void* d_out, int out_size, void* d_ws, size_t ws_size,
                              hipStream_t stream) {
    const float* x    = (const float*)d_in[0];   // [8,1024,768]
    const float* gate = (const float*)d_in[1];   // [8,1024]
    const float* Wqkv = (const float*)d_in[2];   // [768,2304]
    const float* Wmsa = (const float*)d_in[3];   // [768,768]
    const float* bmsa = (const float*)d_in[4];   // [768]
    float* out = (float*)d_out;

    char* ws = (char*)d_ws;
    short* xb  = (short*)(ws);
    short* wtq = (short*)(ws + 12582912);
    short* wtm = (short*)(ws + 16121856);
    short* qb  = (short*)(ws + 17301504);
    short* kb  = (short*)(ws + 29884416);
    short* vt  = (short*)(ws + 42467328);
    short* attn = xb;  // xb fully consumed by k_gemm_qkv before k_attn writes

    k_prep<<<3648, 256, 0, stream>>>(x, gate, xb, Wqkv, wtq, Wmsa, wtm);
    k_gemm_qkv<<<1024, 256, 0, stream>>>(xb, wtq, qb, kb, vt);
    k_attn<<<dim3(96, 8), 256, 0, stream>>>(qb, kb, vt, attn);
    k_gemm_final<<<512, 256, 0, stream>>>(attn, wtm, bmsa, out);
}

// Round 10
// 172.008 us; speedup vs baseline: 1.0405x; 1.0405x over previous
//
#include <hip/hip_runtime.h>
#include <hip/hip_bf16.h>

// Shapes: B=8, N=1024, D=768, H=12, HD=64, 3D=2304, tokens M=8192.
// Workspace layout (bytes), total 55,050,240 (~52.5 MiB):
//   xb   @ 0         : [8192][768]  bf16 (x * gate; reused as attn-out later)
//   wtq  @ 12582912  : [2304][768]  bf16 (W_qkv^T)
//   wtm  @ 16121856  : [768][768]   bf16 (W_msa^T)
//   qb   @ 17301504  : [B,H,N,64]   bf16 (q * SCALE * log2e)
//   kb   @ 29884416  : [B,H,N,64]   bf16 (k)
//   vt   @ 42467328  : [B,H,64,N]   bf16 (v, transposed)

typedef __attribute__((ext_vector_type(8))) short bf8;   // 8 x bf16 (4 VGPRs)
typedef __attribute__((ext_vector_type(4))) float f4;

#define QSCALE 0.1803368801111204f  // (1/8) * log2(e): exp2-domain logits
#define MFMA16 __builtin_amdgcn_mfma_f32_16x16x32_bf16

static __device__ __forceinline__ short bf16_of(float f) {
    union { float f; unsigned u; } a; a.f = f;
    unsigned r = a.u + 0x7FFFu + ((a.u >> 16) & 1u);  // RNE
    return (short)(r >> 16);
}

static __device__ __forceinline__ unsigned bfpk(float lo, float hi) {
    float2 t; t.x = lo; t.y = hi;
    __hip_bfloat162 b = __float22bfloat162_rn(t);
    union { __hip_bfloat162 b; unsigned u; } c; c.b = b;
    return c.u;
}

// async global->LDS, 16 bytes/lane. LDS dest must be wave-uniform base + lane*16.
static __device__ __forceinline__ void async16(const short* g, short* l) {
    __builtin_amdgcn_global_load_lds(
        (const __attribute__((address_space(1))) void*)g,
        (__attribute__((address_space(3))) void*)l, 16, 0, 0);
}

// ---- merged prep kernel: cvt (blocks 0..3071) + Wqkv transpose (3072..3503)
//      + Wmsa transpose (3504..3647). Independent work; saves 2 launch gaps.
static __device__ __forceinline__ void transpose64(
        const float* __restrict__ w, short* __restrict__ wt,
        int K, int E, int k0, int e0, int tid, short (*t)[65]) {
#pragma unroll
    for (int p = 0; p < 16; ++p) {
        int idx = p * 256 + tid;
        int r = idx >> 6, c = idx & 63;
        t[r][c] = bf16_of(w[(k0 + r) * E + e0 + c]);
    }
    __syncthreads();
#pragma unroll
    for (int p = 0; p < 16; ++p) {
        int idx = p * 256 + tid;
        int r = idx >> 6, c = idx & 63;     // r = e offset, c = k offset
        wt[(e0 + r) * K + k0 + c] = t[c][r];
    }
}

__global__ __launch_bounds__(256) void k_prep(
        const float* __restrict__ x, const float* __restrict__ gate,
        short* __restrict__ xb,
        const float* __restrict__ Wqkv, short* __restrict__ wtq,
        const float* __restrict__ Wmsa, short* __restrict__ wtm) {
    __shared__ short t[64][65];
    const int bid = blockIdx.x, tid = threadIdx.x;
    if (bid < 3072) {
        int i = bid * 256 + tid;              // 786432 = 8192*768/8 exactly
        const float g = gate[i / 96];         // row = i*8/768
        const f4* sp = (const f4*)x;
        f4 a = sp[2 * i], b = sp[2 * i + 1];
        union { bf8 v; short h[8]; } o;
        o.h[0] = bf16_of(a[0] * g); o.h[1] = bf16_of(a[1] * g);
        o.h[2] = bf16_of(a[2] * g); o.h[3] = bf16_of(a[3] * g);
        o.h[4] = bf16_of(b[0] * g); o.h[5] = bf16_of(b[1] * g);
        o.h[6] = bf16_of(b[2] * g); o.h[7] = bf16_of(b[7 - 4] * g);
        o.h[6] = bf16_of(b[2] * g); o.h[7] = bf16_of(b[3] * g);
        ((bf8*)xb)[i] = o.v;
    } else if (bid < 3504) {
        int tt = bid - 3072;                  // 432 = 36 x 12
        transpose64(Wqkv, wtq, 768, 2304, (tt / 36) * 64, (tt % 36) * 64, tid, t);
    } else {
        int tt = bid - 3504;                  // 144 = 12 x 12
        transpose64(Wmsa, wtm, 768, 768, (tt / 12) * 64, (tt % 12) * 64, tid, t);
    }
}

// ---- QKV projection: [8192,768] @ [768,2304], tile 128x144, BK=32,
//      QUAD-buffered counted-vmcnt pipeline (T3+T4 restored at 2 blocks/CU).
// R9 diagnosis: the BK=64 dbuf structure ends every tile in vmcnt(0) (full
// drain) -> MfmaUtil 21%. A double buffer FORCES drain-0; >=3 spare tiles of
// LDS enable counted waits. BK=32 quad-buffer = 4 x 8704 shorts = 68 KiB
// (same footprint as R8) -> still 2 blocks/CU, 8 waves/CU, full 256-reg
// budget (acc[2][9]=72 AGPR + ~60 VGPR frags, no spill).
// Pipeline: stage tile t+3 during tile t; steady-state wait vmcnt(10|8)
// per-wave (leaves tiles t+2,t+3 in flight; wave0 issues 5 instr/tile,
// waves1-3 4); vmcnt(0) only at t==22. Epilogue taper t=21: vmcnt(5|4).
// Per tile per wave: 11 ds_read_b128, 18 MFMA (K=32 = one MFMA per acc).
// Swizzle: chunk p holds k-chunk gc=(p&3)^((row>>1)&3) (R6-verified);
// read slot = quad^((row>>1)&3) -> even bank spread on ds_read_b128.
// K-accumulation order ascending k -> bit-identical results to BK=64.
__global__ __launch_bounds__(256, 2) void k_gemm_qkv(
        const short* __restrict__ xb, const short* __restrict__ wtq,
        short* __restrict__ qb, short* __restrict__ kb, short* __restrict__ vt) {
    __shared__ short lds[34816];   // 4 x 8704 shorts = 68 KiB
    const int tid = threadIdx.x, lane = tid & 63;
    const int l16 = lane & 15, quad = lane >> 4;
    const int wm = tid >> 6;       // 4 M-waves; every wave covers all 144 cols

    // XCD swizzle: 1024 blocks = 8 XCDs x 128; each XCD: 8 mI x all 16 nI
    // (B 3.5 MB ~ one XCD L2; A 8x128 rows = 1.6 MB).
    const int wg = blockIdx.x;
    const int swz = (wg & 7) * 128 + (wg >> 3);
    const int mI = swz >> 4, nI = swz & 15;
    const int m0 = mI * 128, n0 = nI * 144;

    const short* gA = xb + m0 * 768;
    const short* gB = wtq + n0 * 768;

    // stage one BK=32 tile: A 128x32 = 512 chunks (2/thr), B 144x32 = 576
    // chunks (2/thr + wave0 extra 64). Wave instr counts: w0=5, w1-3=4.
    auto stage = [&](int buf, int k0) {
        short* base = lds + buf * 8704;
#pragma unroll
        for (int j = 0; j < 2; ++j) {
            int p = j * 256 + tid, row = p >> 2;
            int gc = (p & 3) ^ ((row >> 1) & 3);
            async16(gA + row * 768 + k0 + gc * 8, base + p * 8);
        }
#pragma unroll
        for (int j = 0; j < 2; ++j) {
            int p = j * 256 + tid, row = p >> 2;
            int gc = (p & 3) ^ ((row >> 1) & 3);
            async16(gB + row * 768 + k0 + gc * 8, base + 4096 + p * 8);
        }
        if (tid < 64) {                      // wave 0 only (lanes 0-63)
            int p = 512 + tid, row = p >> 2;
            int gc = (p & 3) ^ ((row >> 1) & 3);
            async16(gB + row * 768 + k0 + gc * 8, base + 4096 + p * 8);
        }
    };

    auto rdA = [&](const short* base, int mf) {
        int row = wm * 32 + mf * 16 + l16;
        return *(const bf8*)(base + row * 32 +
                             ((quad ^ ((row >> 1) & 3)) << 3));
    };
    auto rdB = [&](const short* base, int nf) {
        int row = nf * 16 + l16;
        return *(const bf8*)(base + 4096 + row * 32 +
                             ((quad ^ ((row >> 1) & 3)) << 3));
    };

    f4 z = {0.f, 0.f, 0.f, 0.f};
    f4 acc[2][9];
#pragma unroll
    for (int mf = 0; mf < 2; ++mf)
#pragma unroll
        for (int nf = 0; nf < 9; ++nf) acc[mf][nf] = z;

    // prologue: stage tiles 0,1,2; wait tile 0 (leave 1,2 in flight)
    stage(0, 0); stage(1, 32); stage(2, 64);
    if (wm == 0) asm volatile("s_waitcnt vmcnt(10)" ::: "memory");
    else         asm volatile("s_waitcnt vmcnt(8)" ::: "memory");
    __builtin_amdgcn_s_barrier();

#pragma unroll 4
    for (int t = 0; t < 24; ++t) {
        const short* cur = lds + (t & 3) * 8704;
        bf8 af0 = rdA(cur, 0);
        bf8 af1 = rdA(cur, 1);
        bf8 bfr[9];
#pragma unroll
        for (int nf = 0; nf < 9; ++nf) bfr[nf] = rdB(cur, nf);
        if (t < 21) stage((t + 3) & 3, (t + 3) * 32);
        __builtin_amdgcn_s_setprio(1);
#pragma unroll
        for (int nf = 0; nf < 9; ++nf) {
            acc[0][nf] = MFMA16(af0, bfr[nf], acc[0][nf], 0, 0, 0);
            acc[1][nf] = MFMA16(af1, bfr[nf], acc[1][nf], 0, 0, 0);
        }
        __builtin_amdgcn_s_setprio(0);
        // counted drain: tile t+1 resident after barrier; t+2,t+3 in flight
        if (t < 21) {
            if (wm == 0) asm volatile("s_waitcnt vmcnt(10)" ::: "memory");
            else         asm volatile("s_waitcnt vmcnt(8)" ::: "memory");
        } else if (t == 21) {
            if (wm == 0) asm volatile("s_waitcnt vmcnt(5)" ::: "memory");
            else         asm volatile("s_waitcnt vmcnt(4)" ::: "memory");
        } else if (t == 22) {
            asm volatile("s_waitcnt vmcnt(0)" ::: "memory");
        }
        if (t < 23) __builtin_amdgcn_s_barrier();
    }

    // ---------------- epilogue ----------------
    const int bI = m0 >> 10, nn0 = m0 & 1023;
    // q/k frags: direct stores (frags never straddle q/k/v; 768 % 16 == 0)
#pragma unroll
    for (int nf = 0; nf < 9; ++nf) {
        const int ct = n0 + nf * 16;
        if (ct < 1536) {
            const int which = (ct >= 768) ? 1 : 0;
            const int h = (ct - which * 768) >> 6;
            const int hd = (ct & 63) + l16;
            short* dst = (which ? kb : qb) + (bI * 12 + h) * 65536 + hd;
#pragma unroll
            for (int mf = 0; mf < 2; ++mf)
#pragma unroll
                for (int r = 0; r < 4; ++r) {
                    const int nn = nn0 + wm * 32 + mf * 16 + quad * 4 + r;
                    const float val = acc[mf][nf][r];
                    dst[nn * 64] = bf16_of(which ? val : val * QSCALE);
                }
        }
    }
    // v frags: transpose through LDS in 48-col passes (48 x 136 shorts).
    const int vlo = (n0 >= 1536) ? n0 : 1536;
    const int vcnt = n0 + 144 - vlo;
    const int npass = (vcnt > 0) ? vcnt / 48 : 0;
    for (int p = 0; p < npass; ++p) {
        __syncthreads();
        const int c0 = vlo + p * 48;
#pragma unroll
        for (int nf = 0; nf < 9; ++nf) {
            const int ct = n0 + nf * 16;
            if (ct >= c0 && ct < c0 + 48) {
                const int lcol = ct - c0 + l16;        // 0..47
#pragma unroll
                for (int mf = 0; mf < 2; ++mf)
#pragma unroll
                    for (int r = 0; r < 4; ++r) {
                        const int row = wm * 32 + mf * 16 + quad * 4 + r;
                        lds[lcol * 136 + row] = bf16_of(acc[mf][nf][r]);
                    }
            }
        }
        __syncthreads();
        const int vg0 = c0 - 1536;
#pragma unroll
        for (int u = 0; u < 3; ++u) {
            const int idx = u * 256 + tid;     // 48 cols x 16 chunks = 768
            const int lc = idx >> 4, ck = idx & 15;
            const int vg = vg0 + lc;
            const int h = vg >> 6, hd = vg & 63;
            bf8 vv = *(const bf8*)(lds + lc * 136 + ck * 8);
            *(bf8*)(vt + ((bI * 12 + h) * 64 + hd) * 1024 + nn0 + ck * 8) = vv;
        }
    }
}

// ---- final projection: [8192,768] @ [768,768] + bias -> fp32 out.
// R8-qkv structure: tile 128x96, BK=64, 256 thr as 4M x 1N waves -> per-wave
// 32x96 = acc[2][6] = 48 AGPR. Grid 64m x 8n = 512 blocks = exactly 2
// blocks/CU; LDS dbuf 2 x 14336 shorts = 56 KiB; partner block hides drain.
__global__ __launch_bounds__(256, 2) void k_gemm_final(
        const short* __restrict__ attn, const short* __restrict__ wtm,
        const float* __restrict__ bias, float* __restrict__ out) {
    __shared__ short lds[28672];   // 2 x 14336 shorts = 56 KiB
    const int tid = threadIdx.x, lane = tid & 63;
    const int l16 = lane & 15, quad = lane >> 4, rx = l16 & 7;
    const int wm = tid >> 6;       // 4 M-waves; every wave covers all 96 cols

    // XCD swizzle: 512 blocks = 8 XCDs x 64; each XCD: 8 mI x all 8 nI.
    const int wg = blockIdx.x;
    const int swz = (wg & 7) * 64 + (wg >> 3);
    const int mI = swz >> 3, nI = swz & 7;
    const int m0 = mI * 128, n0 = nI * 96;

    const short* gA = attn + m0 * 768;
    const short* gB = wtm + n0 * 768;

    auto stageA = [&](int buf, int k0) {        // 128x64 = 1024 chunks, 4/thr
        short* base = lds + buf * 14336;
#pragma unroll
        for (int j = 0; j < 4; ++j) {
            int p = j * 256 + tid, row = p >> 3;
            int gc = (p & 7) ^ (row & 7);
            async16(gA + row * 768 + k0 + gc * 8, base + p * 8);
        }
    };
    auto stageB = [&](int buf, int k0) {        // 96x64 = 768 chunks, 3/thr
        short* base = lds + buf * 14336 + 8192;
#pragma unroll
        for (int j = 0; j < 3; ++j) {
            int p = j * 256 + tid, row = p >> 3;
            int gc = (p & 7) ^ (row & 7);
            async16(gB + row * 768 + k0 + gc * 8, base + p * 8);
        }
    };
    auto rdA = [&](const short* base, int mf, int ks) {
        return *(const bf8*)(base + (wm * 32 + mf * 16 + l16) * 64 +
                             (((ks * 4 + quad) ^ rx) << 3));
    };
    auto rdB = [&](const short* base, int nf, int ks) {
        return *(const bf8*)(base + 8192 + (nf * 16 + l16) * 64 +
                             (((ks * 4 + quad) ^ rx) << 3));
    };

    f4 z = {0.f, 0.f, 0.f, 0.f};
    f4 acc[2][6];
#pragma unroll
    for (int mf = 0; mf < 2; ++mf)
#pragma unroll
        for (int nf = 0; nf < 6; ++nf) acc[mf][nf] = z;

    stageA(0, 0); stageB(0, 0);
    asm volatile("s_waitcnt vmcnt(0)" ::: "memory");
    __builtin_amdgcn_s_barrier();

#pragma unroll 2
    for (int t = 0; t < 12; ++t) {
        const short* cur = lds + (t & 1) * 14336;
        // ---- phase 1: nf 0-2 ----
        bf8 af[2][2];
        af[0][0] = rdA(cur, 0, 0); af[0][1] = rdA(cur, 0, 1);
        af[1][0] = rdA(cur, 1, 0); af[1][1] = rdA(cur, 1, 1);
        bf8 bfr[3][2];
#pragma unroll
        for (int nf = 0; nf < 3; ++nf) { bfr[nf][0] = rdB(cur, nf, 0); bfr[nf][1] = rdB(cur, nf, 1); }
        if (t < 11) stageA((t + 1) & 1, (t + 1) * 64);
        __builtin_amdgcn_s_setprio(1);
#pragma unroll
        for (int mf = 0; mf < 2; ++mf)
#pragma unroll
            for (int nf = 0; nf < 3; ++nf) {
                acc[mf][nf] = MFMA16(af[mf][0], bfr[nf][0], acc[mf][nf], 0, 0, 0);
                acc[mf][nf] = MFMA16(af[mf][1], bfr[nf][1], acc[mf][nf], 0, 0, 0);
            }
        __builtin_amdgcn_s_setprio(0);
        // ---- phase 2: nf 3-5 ----
        bf8 bfh[3][2];
#pragma unroll
        for (int nf = 0; nf < 3; ++nf) { bfh[nf][0] = rdB(cur, nf + 3, 0); bfh[nf][1] = rdB(cur, nf + 3, 1); }
        if (t < 11) stageB((t + 1) & 1, (t + 1) * 64);
        __builtin_amdgcn_s_setprio(1);
#pragma unroll
        for (int mf = 0; mf < 2; ++mf)
#pragma unroll
            for (int nf = 0; nf < 3; ++nf) {
                acc[mf][nf + 3] = MFMA16(af[mf][0], bfh[nf][0], acc[mf][nf + 3], 0, 0, 0);
                acc[mf][nf + 3] = MFMA16(af[mf][1], bfh[nf][1], acc[mf][nf + 3], 0, 0, 0);
            }
        __builtin_amdgcn_s_setprio(0);
        asm volatile("s_waitcnt vmcnt(0)" ::: "memory");
        __builtin_amdgcn_s_barrier();
    }

    // epilogue: fp32 + bias
#pragma unroll
    for (int nf = 0; nf < 6; ++nf) {
        const int e = n0 + nf * 16 + l16;
        const float bv = bias[e];
#pragma unroll
        for (int mf = 0; mf < 2; ++mf)
#pragma unroll
            for (int r = 0; r < 4; ++r) {
                const int row = m0 + wm * 32 + mf * 16 + quad * 4 + r;
                out[row * 768 + e] = acc[mf][nf][r] + bv;
            }
    }
}

// ---- flash attention: 4 waves x 32 q-rows (256-thread block), grid (96,8)
//      = 768 blocks -> exactly 3 co-resident blocks/CU (launch_bounds(256,3)).
// Two q-groups per wave SHARE the K and V LDS fragments: ds_read per MFMA
// halves, per-wave ILP doubles, barrier cost per unit work halves.
// Blocks are independent -> setprio(1) around MFMA clusters (T5, m191).
// S-MFMA set A uses K rows sigma(p)=8*(p>>2)+(p&3), set B rows sigma(p)+4.
// lane(l16,quad) regs [A0..A3,B0..B3] = P[m=l16][j=quad*8+0..7]: the PV
// B-operand directly -- no cross-lane transform needed.
// LDS swizzle f(row)=4*((row>>3)&1)+(row&3) keeps sigma-reads at 2 lanes/bank.
__global__ __launch_bounds__(256, 3) void k_attn(const short* __restrict__ qb,
                                                 const short* __restrict__ kb,
                                                 const short* __restrict__ vt,
                                                 short* __restrict__ attn) {
    __shared__ short Ks[2][4096];     // [64 keys][8 slots], f-swizzled
    __shared__ short Vs[2][4096];     // [64 dims][8 slots], f-swizzled
    const int tid = threadIdx.x, wave = tid >> 6, lane = tid & 63;
    const int l16 = lane & 15, quad = lane >> 4;
    const int bh = blockIdx.x;             // b*12 + h
    const int b = bh / 12, h = bh - b * 12;
    const int m_base = blockIdx.y * 128 + wave * 32;  // 32 q-rows per wave
    const short* qh = qb + bh * 65536;
    const short* kh = kb + bh * 65536;
    const short* vh = vt + bh * 65536;     // [64][1024]

    // K-read offsets: set A row rA = sigma(l16), set B row rA+4 (f identical)
    const int rA = ((l16 >> 2) << 3) + (l16 & 3);
    const int fK = (((rA >> 3) & 1) << 2) + (rA & 3);
    const int sK = (quad ^ fK) * 8;              // slot*8 for d-chunk=quad
    const int oAlo = rA * 64 + sK;               // d 0..31
    const int oAhi = rA * 64 + (sK ^ 32);        // d 32..63 (slot^4)
    const int oBlo = oAlo + 256, oBhi = oAhi + 256;  // row+4
    // V-read offset: row = dt*16+l16, chunk = (jj>>3)+quad
    const int fV = (((l16 >> 3) & 1) << 2) + (l16 & 3);
    const int oV = l16 * 64 + ((quad ^ fV) * 8); // jj=32 -> ^32

    // Q^T b-frags for both 16-row groups (fixed for whole loop)
    const short* qp0 = qh + (m_base + l16) * 64 + quad * 8;
    bf8 qf00 = *(const bf8*)(qp0);
    bf8 qf01 = *(const bf8*)(qp0 + 32);
    const short* qp1 = qp0 + 16 * 64;
    bf8 qf10 = *(const bf8*)(qp1);
    bf8 qf11 = *(const bf8*)(qp1 + 32);

    union { bf8 v; short h[8]; } onef;
#pragma unroll
    for (int i = 0; i < 8; ++i) onef.h[i] = (short)0x3F80;  // bf16 1.0

    f4 z = {0.f, 0.f, 0.f, 0.f};
    f4 acc0[4] = {z, z, z, z};             // out^T group 0: 4 d-tiles
    f4 acc1[4] = {z, z, z, z};             // out^T group 1
    f4 accl0 = z, accl1 = z;               // P row-sums via ones-MFMA

    auto stage = [&](int buf, int j0) {
        // 256 threads x 2: 512 chunks each for K and V
#pragma unroll
        for (int j = 0; j < 2; ++j) {
            int idx = j * 256 + tid;
            int row = idx >> 3;
            int fr = (((row >> 3) & 1) << 2) + (row & 3);
            int gc = (idx & 7) ^ fr;        // slot idx&7 holds chunk gc
            async16(kh + (j0 + row) * 64 + gc * 8, Ks[buf] + idx * 8);
            async16(vh + row * 1024 + j0 + gc * 8, Vs[buf] + idx * 8);
        }
    };

    stage(0, 0);
    int cur = 0;
    for (int it = 0; it < 16; ++it) {
        __builtin_amdgcn_s_waitcnt(0);         // own DMA for tile[cur] drained
        __syncthreads();                       // => tile[cur] resident for all
        if (it + 1 < 16) stage(cur ^ 1, (it + 1) * 64);  // overlaps compute
        const short* Kc = Ks[cur];
        const short* Vc = Vs[cur];

#pragma unroll
        for (int jj = 0; jj < 64; jj += 32) {
            const short* kjj = Kc + jj * 64;
            bf8 kAlo = *(const bf8*)(kjj + oAlo);
            bf8 kAhi = *(const bf8*)(kjj + oAhi);
            bf8 kBlo = *(const bf8*)(kjj + oBlo);
            bf8 kBhi = *(const bf8*)(kjj + oBhi);
            bf8 vf0 = *(const bf8*)(Vc + 0 * 1024 + (oV ^ (jj ? 32 : 0)));
            bf8 vf1 = *(const bf8*)(Vc + 1 * 1024 + (oV ^ (jj ? 32 : 0)));
            bf8 vf2 = *(const bf8*)(Vc + 2 * 1024 + (oV ^ (jj ? 32 : 0)));
            bf8 vf3 = *(const bf8*)(Vc + 3 * 1024 + (oV ^ (jj ? 32 : 0)));

            // ----- group 0 -----
            {
                f4 sA = z, sB = z;
                __builtin_amdgcn_s_setprio(1);
                sA = MFMA16(kAlo, qf00, sA, 0, 0, 0);
                sA = MFMA16(kAhi, qf01, sA, 0, 0, 0);
                sB = MFMA16(kBlo, qf00, sB, 0, 0, 0);
                sB = MFMA16(kBhi, qf01, sB, 0, 0, 0);
                __builtin_amdgcn_s_setprio(0);
                float a0 = __builtin_amdgcn_exp2f(sA[0]);
                float a1 = __builtin_amdgcn_exp2f(sA[1]);
                float a2 = __builtin_amdgcn_exp2f(sA[2]);
                float a3 = __builtin_amdgcn_exp2f(sA[3]);
                float b0 = __builtin_amdgcn_exp2f(sB[0]);
                float b1 = __builtin_amdgcn_exp2f(sB[1]);
                float b2 = __builtin_amdgcn_exp2f(sB[2]);
                float b3 = __builtin_amdgcn_exp2f(sB[3]);
                union { bf8 v; unsigned u[4]; } p;
                p.u[0] = bfpk(a0, a1); p.u[1] = bfpk(a2, a3);
                p.u[2] = bfpk(b0, b1); p.u[3] = bfpk(b2, b3);
                __builtin_amdgcn_s_setprio(1);
                accl0 = MFMA16(onef.v, p.v, accl0, 0, 0, 0);
                acc0[0] = MFMA16(vf0, p.v, acc0[0], 0, 0, 0);
                acc0[1] = MFMA16(vf1, p.v, acc0[1], 0, 0, 0);
                acc0[2] = MFMA16(vf2, p.v, acc0[2], 0, 0, 0);
                acc0[3] = MFMA16(vf3, p.v, acc0[3], 0, 0, 0);
                __builtin_amdgcn_s_setprio(0);
            }
            // ----- group 1 (shares kA/kB/vf frags) -----
            {
                f4 sA = z, sB = z;
                __builtin_amdgcn_s_setprio(1);
                sA = MFMA16(kAlo, qf10, sA, 0, 0, 0);
                sA = MFMA16(kAhi, qf11, sA, 0, 0, 0);
                sB = MFMA16(kBlo, qf10, sB, 0, 0, 0);
                sB = MFMA16(kBhi, qf11, sB, 0, 0, 0);
                __builtin_amdgcn_s_setprio(0);
                float a0 = __builtin_amdgcn_exp2f(sA[0]);
                float a1 = __builtin_amdgcn_exp2f(sA[1]);
                float a2 = __builtin_amdgcn_exp2f(sA[2]);
                float a3 = __builtin_amdgcn_exp2f(sA[3]);
                float b0 = __builtin_amdgcn_exp2f(sB[0]);
                float b1 = __builtin_amdgcn_exp2f(sB[1]);
                float b2 = __builtin_amdgcn_exp2f(sB[2]);
                float b3 = __builtin_amdgcn_exp2f(sB[3]);
                union { bf8 v; unsigned u[4]; } p;
                p.u[0] = bfpk(a0, a1); p.u[1] = bfpk(a2, a3);
                p.u[2] = bfpk(b0, b1); p.u[3] = bfpk(b2, b3);
                __builtin_amdgcn_s_setprio(1);
                accl1 = MFMA16(onef.v, p.v, accl1, 0, 0, 0);
                acc1[0] = MFMA16(vf0, p.v, acc1[0], 0, 0, 0);
                acc1[1] = MFMA16(vf1, p.v, acc1[1], 0, 0, 0);
                acc1[2] = MFMA16(vf2, p.v, acc1[2], 0, 0, 0);
                acc1[3] = MFMA16(vf3, p.v, acc1[3], 0, 0, 0);
                __builtin_amdgcn_s_setprio(0);
            }
        }
        cur ^= 1;
    }

    const float inv0 = 1.f / accl0[0];
    const float inv1 = 1.f / accl1[0];
    const int row0 = (b << 10) + m_base + l16;
    short* op0 = attn + row0 * 768 + h * 64 + quad * 4;
    short* op1 = op0 + 16 * 768;
#pragma unroll
    for (int dt = 0; dt < 4; ++dt)
#pragma unroll
        for (int r = 0; r < 4; ++r) {
            op0[dt * 16 + r] = bf16_of(acc0[dt][r] * inv0);
            op1[dt * 16 + r] = bf16_of(acc1[dt][r] * inv1);
        }
}

extern "C" void kernel_launch(void* const* d_in, const int* in_sizes, int n_in,
                              void* d_out, int out_size, void* d_ws, size_t ws_size,
                              hipStream_t stream) {
    const float* x    = (const float*)d_in[0];   // [8,1024,768]
    const float* gate = (const float*)d_in[1];   // [8,1024]
    const float* Wqkv = (const float*)d_in[2];   // [768,2304]
    const float* Wmsa = (const float*)d_in[3];   // [768,768]
    const float* bmsa = (const float*)d_in[4];   // [768]
    float* out = (float*)d_out;

    char* ws = (char*)d_ws;
    short* xb  = (short*)(ws);
    short* wtq = (short*)(ws + 12582912);
    short* wtm = (short*)(ws + 16121856);
    short* qb  = (short*)(ws + 17301504);
    short* kb  = (short*)(ws + 29884416);
    short* vt  = (short*)(ws + 42467328);
    short* attn = xb;  // xb fully consumed by k_gemm_qkv before k_attn writes

    k_prep<<<3648, 256, 0, stream>>>(x, gate, xb, Wqkv, wtq, Wmsa, wtm);
    k_gemm_qkv<<<1024, 256, 0, stream>>>(xb, wtq, qb, kb, vt);
    k_attn<<<dim3(96, 8), 256, 0, stream>>>(qb, kb, vt, attn);
    k_gemm_final<<<512, 256, 0, stream>>>(attn, wtm, bmsa, out);
}